// Round 10
// baseline (1734.095 us; speedup 1.0000x reference)
//
#include <hip/hip_runtime.h>
#include <math.h>

#define BB 32
#define NN 1000
#define CC 128
#define FF 128
#define OO 64
#define CAP 128
#define NB 40

// exact replica of JAX's np.float32(1.0 - 0.8) = 0.20000000298023224f
#define RMC ((float)(1.0 - 0.8))

// ---- CSR build + stage-1 D/dg + fused pre-work (blocks with i==NN) ----
// masked rows (all-zero in A, pre-masked) skipped.
__global__ void k_csr(const float* __restrict__ A, const float* __restrict__ mask,
                      const int* __restrict__ Nn,
                      const float* __restrict__ p0, const float* __restrict__ p1,
                      const float* __restrict__ W0, const float* __restrict__ W1,
                      const float* __restrict__ W2,
                      short* __restrict__ idx, int* __restrict__ cnt,
                      float* __restrict__ D, float* __restrict__ dg,
                      float* __restrict__ m, float* __restrict__ gate,
                      int* __restrict__ ncur0, float* __restrict__ pn,
                      float* __restrict__ Wt){
  int i = blockIdx.x, b = blockIdx.y, lane = threadIdx.x;   // block = 64 (one wave)
  if (i == NN){                            // ---- 32 pre-work blocks ----
    for (int j = lane; j < NN; j += 64){
      float v = mask[b*NN + j]; m[b*NN + j] = v; gate[b*NN + j] = v;
    }
    if (lane == 0) ncur0[b] = Nn[b];
    if (b == 0 && lane == 1){ float s=0.f; for(int c=0;c<FF;c++) s += p0[c]*p0[c]; pn[0] = sqrtf(s); }
    if (b == 1 && lane == 1){ float s=0.f; for(int c=0;c<FF;c++) s += p1[c]*p1[c]; pn[1] = sqrtf(s); }
    // Wt[s][c][f] = W[s][f][c]; 3*FF*CC = 49152 elems, 1536 per block
    for (int e = b*1536 + lane; e < (b+1)*1536; e += 64){
      int s = e / (FF*CC), rem = e % (FF*CC);
      int c = rem >> 7, f = rem & 127;
      const float* W = (s == 0) ? W0 : (s == 1) ? W1 : W2;
      Wt[(size_t)s*FF*CC + rem] = W[f*CC + c];
    }
    return;
  }
  if (mask[b*NN + i] == 0.f){              // A row is all-zero (A pre-masked)
    if (lane == 0){
      cnt[b*NN + i] = 0;
      D[b*NN + i]  = 1.0f / sqrtf(1.0f + 1e-5f);
      dg[b*NN + i] = 0.f;
    }
    return;
  }
  const float4* row = (const float4*)(A + ((size_t)b*NN + i)*NN);
  short* out = idx + ((size_t)b*NN + i)*CAP;
  int count = 0;
  for (int base = 0; base < 250; base += 64){               // 1000 = 250 float4
    int q = base + lane;
    float4 v;
    if (q < 250) v = row[q]; else { v.x=v.y=v.z=v.w=0.f; }
    int lc = (v.x!=0.f) + (v.y!=0.f) + (v.z!=0.f) + (v.w!=0.f);
    int pre = lc;
    #pragma unroll
    for (int off = 1; off < 64; off <<= 1){
      int t = __shfl_up(pre, off);
      if (lane >= off) pre += t;
    }
    int tot = __shfl(pre, 63);
    pre -= lc;                                              // exclusive prefix
    int slot = count + pre;
    int j = q*4;
    if (v.x!=0.f && slot < CAP) out[slot++] = (short)j;
    if (v.y!=0.f && slot < CAP) out[slot++] = (short)(j+1);
    if (v.z!=0.f && slot < CAP) out[slot++] = (short)(j+2);
    if (v.w!=0.f && slot < CAP) out[slot++] = (short)(j+3);
    count += tot;
  }
  if (lane == 0){
    int cn = (count < CAP) ? count : CAP;
    cnt[b*NN + i] = cn;
    // stage-1 degree: A pre-masked => every CSR neighbor has mask=1
    float Dv = 1.0f / sqrtf((float)cn + 1.0f + 1e-5f);
    D[b*NN + i]  = Dv;
    dg[b*NN + i] = Dv;                   // mask_i == 1 here
  }
}

// ---- Y_i = sum_nbr dg_j*h_j ; T_i = D_i*Y + D_i^2*(gate_i*h_i) ----
// float4 gather (16 B/lane), 4 groups of 32 lanes; staging-time compaction drops
// dn==0 edges (order-preserving); gather loop branch-free (R6 lesson).
__global__ void k_aggt(const short* __restrict__ idx, const int* __restrict__ cnt,
                       const float* __restrict__ D, const float* __restrict__ dg,
                       const float* __restrict__ m, const float* __restrict__ gate,
                       const float* __restrict__ h, float* __restrict__ T){
  __shared__ int   nb[CAP];                // row offsets j*CC (compacted)
  __shared__ float dn[CAP];
  __shared__ float red[4][CC];             // cross-group partials (2 KB)
  __shared__ int   wtot[2];
  int blk = blockIdx.x;                    // XCD swizzle: same b lands on same XCD
  int b = (blk & 7) + 8*((blk >> 3) & 3);
  int i = blk >> 5;
  int tid = threadIdx.x;                   // block = 128
  size_t orow = ((size_t)b*NN + i)*CC;
  if (m[b*NN + i] == 0.f){                 // masked target: T row must be zero
    T[orow + tid] = 0.f;
    return;
  }
  int n = cnt[b*NN + i];
  const short* r = idx + ((size_t)b*NN + i)*CAP;
  // --- compaction: keep edges with dn != 0, preserve order ---
  int j = 0; float d = 0.f; bool keep = false;
  if (tid < n){ j = (int)r[tid]; d = dg[b*NN + j]; keep = (d != 0.f); }
  unsigned long long ball = __ballot(keep);
  int lane64 = tid & 63, wv = tid >> 6;
  int pre = __popcll(ball & ((1ull << lane64) - 1ull));
  if (lane64 == 0) wtot[wv] = __popcll(ball);
  __syncthreads();
  int base = (wv == 1) ? wtot[0] : 0;
  if (keep){ nb[base + pre] = j*CC; dn[base + pre] = d; }
  int nlive = wtot[0] + wtot[1];
  int np = (nlive + 15) & ~15;             // pad to 16 (CAP=128 safe)
  for (int q = nlive + tid; q < np; q += 128){ nb[q] = 0; dn[q] = 0.f; }
  __syncthreads();
  // --- branch-free float4 gather: group g handles edges k+g, k+g+4, k+g+8, k+g+12 ---
  int g = tid >> 5, lane = tid & 31;
  const float* hb = h + (size_t)b*NN*CC;
  float4 a0 = {0.f,0.f,0.f,0.f}, a1 = a0, a2 = a0, a3 = a0;
  for (int k = 0; k < np; k += 16){
    int e = k + g;
    float4 v0 = *(const float4*)(hb + nb[e   ] + (lane<<2));
    float4 v1 = *(const float4*)(hb + nb[e+ 4] + (lane<<2));
    float4 v2 = *(const float4*)(hb + nb[e+ 8] + (lane<<2));
    float4 v3 = *(const float4*)(hb + nb[e+12] + (lane<<2));
    float d0 = dn[e], d1 = dn[e+4], d2 = dn[e+8], d3 = dn[e+12];
    a0.x += d0*v0.x; a0.y += d0*v0.y; a0.z += d0*v0.z; a0.w += d0*v0.w;
    a1.x += d1*v1.x; a1.y += d1*v1.y; a1.z += d1*v1.z; a1.w += d1*v1.w;
    a2.x += d2*v2.x; a2.y += d2*v2.y; a2.z += d2*v2.z; a2.w += d2*v2.w;
    a3.x += d3*v3.x; a3.y += d3*v3.y; a3.z += d3*v3.z; a3.w += d3*v3.w;
  }
  float4 Yv;
  Yv.x = (a0.x + a1.x) + (a2.x + a3.x);
  Yv.y = (a0.y + a1.y) + (a2.y + a3.y);
  Yv.z = (a0.z + a1.z) + (a2.z + a3.z);
  Yv.w = (a0.w + a1.w) + (a2.w + a3.w);
  *(float4*)&red[g][lane<<2] = Yv;
  __syncthreads();
  int c = tid;
  float Y = (red[0][c] + red[1][c]) + (red[2][c] + red[3][c]);
  float Di = D[b*NN + i];
  float gi = gate[b*NN + i];
  T[orow + c] = Di*Y + Di*Di*(gi*hb[(size_t)i*CC + c]);
}

// ---- H = relu(T @ W^T + b)*m + fused pool score (stages 1,2) ----
// GEMM body identical to R3's k_lin (which runs <75 µs, no spill). NO launch_bounds:
// R5's spill came from the (256,2) VGPR clamp (128 VGPR -> ~1.5 GB phantom traffic).
// Score epilogue adds only a 4-term dot + 5 shfl after accs are live-range-dead.
__global__ void k_lins(const float* __restrict__ T, const float* __restrict__ m,
                       const float* __restrict__ Wt,   // [cc][f] transposed
                       const float* __restrict__ bias,
                       const float* __restrict__ p, const float* __restrict__ pn,
                       float* __restrict__ Hout, float* __restrict__ ysc){
  __shared__ float t[NB][CC];              // 20.5 KB
  int b = blockIdx.y, tid = threadIdx.x;   // block = 256
  int i0 = blockIdx.x * NB;
  const float4* Tg = (const float4*)(T + ((size_t)b*NN + i0)*CC);
  float4* tl = (float4*)&t[0][0];
  #pragma unroll
  for (int e = 0; e < 5; e++) tl[tid + e*256] = Tg[tid + e*256];  // 1280 float4
  __syncthreads();
  int fg = tid & 31;                       // 4 consecutive f per thread
  int nr = tid >> 5;                       // 0..7 node-row
  float acc[5][4];
  float4 bi = ((const float4*)bias)[fg];
  #pragma unroll
  for (int n5 = 0; n5 < 5; n5++){
    acc[n5][0]=bi.x; acc[n5][1]=bi.y; acc[n5][2]=bi.z; acc[n5][3]=bi.w;
  }
  for (int c4 = 0; c4 < 32; c4++){
    float4 tv[5];
    #pragma unroll
    for (int n5 = 0; n5 < 5; n5++)
      tv[n5] = *((const float4*)&t[nr + n5*8][c4*4]);
    #pragma unroll
    for (int k = 0; k < 4; k++){
      float4 wv = ((const float4*)Wt)[(size_t)(c4*4 + k)*32 + fg];
      #pragma unroll
      for (int n5 = 0; n5 < 5; n5++){
        float tvv = (k==0) ? tv[n5].x : (k==1) ? tv[n5].y : (k==2) ? tv[n5].z : tv[n5].w;
        acc[n5][0] += tvv*wv.x; acc[n5][1] += tvv*wv.y;
        acc[n5][2] += tvv*wv.z; acc[n5][3] += tvv*wv.w;
      }
    }
  }
  float pn0 = pn[0];
  float4 p4 = ((const float4*)p)[fg];
  #pragma unroll
  for (int n5 = 0; n5 < 5; n5++){
    int i = i0 + nr + n5*8;
    float mi = m[b*NN + i];
    float4 o4;
    o4.x = fmaxf(acc[n5][0], 0.f)*mi;
    o4.y = fmaxf(acc[n5][1], 0.f)*mi;
    o4.z = fmaxf(acc[n5][2], 0.f)*mi;
    o4.w = fmaxf(acc[n5][3], 0.f)*mi;
    ((float4*)&Hout[((size_t)b*NN + i)*CC])[fg] = o4;
    float s = o4.x*p4.x + o4.y*p4.y + o4.z*p4.z + o4.w*p4.w;
    s += __shfl_xor(s, 16);
    s += __shfl_xor(s, 8);
    s += __shfl_xor(s, 4);
    s += __shfl_xor(s, 2);
    s += __shfl_xor(s, 1);
    if (fg == 0) ysc[b*NN + i] = s / pn0;
  }
}

// ---- H = relu(T @ W^T + b)*m ---- (stage 3: pristine R3 body, no epilogue)
__global__ void k_lin(const float* __restrict__ T, const float* __restrict__ m,
                      const float* __restrict__ Wt,   // [cc][f] transposed
                      const float* __restrict__ bias, float* __restrict__ Hout){
  __shared__ float t[NB][CC];              // 20.5 KB
  int b = blockIdx.y, tid = threadIdx.x;   // block = 256
  int i0 = blockIdx.x * NB;
  const float4* Tg = (const float4*)(T + ((size_t)b*NN + i0)*CC);
  float4* tl = (float4*)&t[0][0];
  #pragma unroll
  for (int e = 0; e < 5; e++) tl[tid + e*256] = Tg[tid + e*256];  // 1280 float4
  __syncthreads();
  int fg = tid & 31;                       // 4 consecutive f per thread
  int nr = tid >> 5;                       // 0..7 node-row
  float acc[5][4];
  float4 bi = ((const float4*)bias)[fg];
  #pragma unroll
  for (int n5 = 0; n5 < 5; n5++){
    acc[n5][0]=bi.x; acc[n5][1]=bi.y; acc[n5][2]=bi.z; acc[n5][3]=bi.w;
  }
  for (int c4 = 0; c4 < 32; c4++){
    float4 tv[5];
    #pragma unroll
    for (int n5 = 0; n5 < 5; n5++)
      tv[n5] = *((const float4*)&t[nr + n5*8][c4*4]);
    #pragma unroll
    for (int k = 0; k < 4; k++){
      float4 wv = ((const float4*)Wt)[(size_t)(c4*4 + k)*32 + fg];
      #pragma unroll
      for (int n5 = 0; n5 < 5; n5++){
        float tvv = (k==0) ? tv[n5].x : (k==1) ? tv[n5].y : (k==2) ? tv[n5].z : tv[n5].w;
        acc[n5][0] += tvv*wv.x; acc[n5][1] += tvv*wv.y;
        acc[n5][2] += tvv*wv.z; acc[n5][3] += tvv*wv.w;
      }
    }
  }
  #pragma unroll
  for (int n5 = 0; n5 < 5; n5++){
    int i = i0 + nr + n5*8;
    float mi = m[b*NN + i];
    float4 o4;
    o4.x = fmaxf(acc[n5][0], 0.f)*mi;
    o4.y = fmaxf(acc[n5][1], 0.f)*mi;
    o4.z = fmaxf(acc[n5][2], 0.f)*mi;
    o4.w = fmaxf(acc[n5][3], 0.f)*mi;
    ((float4*)&Hout[((size_t)b*NN + i)*CC])[fg] = o4;
  }
}

// ---------------- top-k pool: 1 node/thread, float4 LDS scan, ping-pong ncur ----------------
__global__ void k_pool(const float* __restrict__ y, float* __restrict__ m,
                       const int* __restrict__ ncur_in, int* __restrict__ ncur_out,
                       float* __restrict__ gate){
  __shared__ float yk[NN];
  int b = blockIdx.y, tid = threadIdx.x;   // grid (4, BB), block = 256
  int i = blockIdx.x*256 + tid;
  for (int j = tid; j < NN; j += 256)
    yk[j] = (m[b*NN + j] > 0.f) ? y[b*NN + j] : INFINITY;
  __syncthreads();
  int n = ncur_in[b];
  int nr = (int)((float)n * RMC);          // exact JAX semantics (f32 mult, trunc)
  float myv = (i < NN) ? yk[i] : INFINITY;
  int cnt = 0;
  const float4* yk4 = (const float4*)yk;   // broadcast reads: conflict-free
  #pragma unroll 5
  for (int q = 0; q < 250; q++){
    float4 v = yk4[q];
    int j0 = q*4;
    cnt += (int)((v.x < myv) || (v.x == myv && j0     < i));
    cnt += (int)((v.y < myv) || (v.y == myv && j0 + 1 < i));
    cnt += (int)((v.z < myv) || (v.z == myv && j0 + 2 < i));
    cnt += (int)((v.w < myv) || (v.w == myv && j0 + 3 < i));
  }
  if (i < NN){
    bool keep = (cnt >= nr) && (m[b*NN + i] > 0.f);
    m[b*NN + i]    = keep ? 1.0f : 0.0f;
    gate[b*NN + i] = keep ? tanhf(y[b*NN + i]) : 0.0f;
  }
  if (blockIdx.x == 0 && tid == 0) ncur_out[b] = n - nr;
}

// ---------------- degree from new mask -> D, dg = D*gate ----------------
__global__ void k_deg(const short* __restrict__ idx, const int* __restrict__ cnt,
                      const float* __restrict__ m, const float* __restrict__ gate,
                      float* __restrict__ D, float* __restrict__ dg){
  __shared__ float ml[NN];
  int b = blockIdx.y, tid = threadIdx.x;   // grid (4, BB), block = 256
  for (int i = tid; i < NN; i += 256) ml[i] = m[b*NN + i];
  __syncthreads();
  int j = blockIdx.x*250 + tid;
  if (tid < 250){
    const short* r = idx + ((size_t)b*NN + j)*CAP;
    int n = cnt[b*NN + j];
    float s0=0.f, s1=0.f, s2=0.f, s3=0.f;
    int k = 0;
    for (; k+4 <= n; k += 4){
      s0 += ml[r[k]]; s1 += ml[r[k+1]]; s2 += ml[r[k+2]]; s3 += ml[r[k+3]];
    }
    for (; k < n; k++) s0 += ml[r[k]];
    float Dv = 1.0f / sqrtf(((s0+s1)+(s2+s3)) + 1.0f + 1e-5f);
    D[b*NN + j]  = Dv;
    dg[b*NN + j] = Dv * gate[b*NN + j];
  }
}

// ---------------- partial global max pool (masked rows skipped; relu => max>=0) ----------------
__global__ void k_fmax(const float* __restrict__ H, const float* __restrict__ m,
                       float* __restrict__ part){
  int sx = blockIdx.x, b = blockIdx.y, c = threadIdx.x;   // grid (8, BB), block = 128
  float mx = 0.f;
  int i0 = sx*125;
  for (int i = i0; i < i0+125; i++){
    if (m[b*NN + i] != 0.f)
      mx = fmaxf(mx, H[((size_t)b*NN + i)*CC + c]);
  }
  part[((size_t)b*8 + sx)*CC + c] = mx;
}

// ---------------- combine partial maxima + FC ----------------
__global__ void k_fc(const float* __restrict__ part, const float* __restrict__ Wfc,
                     const float* __restrict__ bfc, float* __restrict__ out){
  __shared__ float g[FF];
  int b = blockIdx.x, tid = threadIdx.x;   // block = 128
  float mx = 0.f;
  #pragma unroll
  for (int s = 0; s < 8; s++) mx = fmaxf(mx, part[((size_t)b*8 + s)*CC + tid]);
  g[tid] = mx;
  __syncthreads();
  if (tid < OO){
    float acc = bfc[tid];
    for (int c = 0; c < FF; c++) acc += g[c]*Wfc[tid*FF + c];
    out[b*OO + tid] = acc;
  }
}

extern "C" void kernel_launch(void* const* d_in, const int* in_sizes, int n_in,
                              void* d_out, int out_size, void* d_ws, size_t ws_size,
                              hipStream_t stream) {
  const float* x    = (const float*)d_in[0];
  const float* A    = (const float*)d_in[1];
  const float* mask = (const float*)d_in[2];
  const int*   Nn   = (const int*)  d_in[3];
  const float* W0   = (const float*)d_in[4];
  const float* b0   = (const float*)d_in[5];
  const float* W1   = (const float*)d_in[6];
  const float* b1   = (const float*)d_in[7];
  const float* W2   = (const float*)d_in[8];
  const float* b2   = (const float*)d_in[9];
  const float* p0   = (const float*)d_in[10];
  const float* p1   = (const float*)d_in[11];
  const float* Wfc  = (const float*)d_in[12];
  const float* bfc  = (const float*)d_in[13];
  float* out = (float*)d_out;

  // workspace carve (~42 MB)
  char* w = (char*)d_ws;
  float* H   = (float*)w; w += (size_t)BB*NN*CC*4;      // 16.38 MB
  float* T   = (float*)w; w += (size_t)BB*NN*CC*4;      // 16.38 MB
  short* idx = (short*)w; w += (size_t)BB*NN*CAP*2;     // 8.19 MB
  float* Wt  = (float*)w; w += (size_t)3*FF*CC*4;       // 192 KB
  float* part= (float*)w; w += (size_t)8*BB*CC*4;       // 131 KB
  int*   cnt = (int*)w;   w += (size_t)BB*NN*4;
  float* D   = (float*)w; w += (size_t)BB*NN*4;
  float* m   = (float*)w; w += (size_t)BB*NN*4;
  float* ysc = (float*)w; w += (size_t)BB*NN*4;
  float* gate= (float*)w; w += (size_t)BB*NN*4;
  float* dg  = (float*)w; w += (size_t)BB*NN*4;
  int*   ncur= (int*)w;   w += 3*BB*sizeof(int);        // ping-pong slots
  float* pn  = (float*)w; w += 64;

  // CSR + all pre-work in one dispatch (grid has 32 extra i==NN blocks)
  k_csr<<<dim3(NN + 1, BB), 64, 0, stream>>>(A, mask, Nn, p0, p1, W0, W1, W2,
                                             idx, cnt, D, dg, m, gate, ncur, pn, Wt);

  // ---- stage 1: x -> H (score fused into lin) ----
  k_aggt<<<BB*NN, 128, 0, stream>>>(idx, cnt, D, dg, m, gate, x, T);
  k_lins<<<dim3(25, BB), 256, 0, stream>>>(T, m, Wt + 0*FF*CC, b0, p0, pn + 0, H, ysc);
  k_pool<<<dim3(4, BB), 256, 0, stream>>>(ysc, m, ncur + 0*BB, ncur + 1*BB, gate);
  k_deg<<<dim3(4, BB), 256, 0, stream>>>(idx, cnt, m, gate, D, dg);

  // ---- stage 2: H -> H ----
  k_aggt<<<BB*NN, 128, 0, stream>>>(idx, cnt, D, dg, m, gate, H, T);
  k_lins<<<dim3(25, BB), 256, 0, stream>>>(T, m, Wt + 1*FF*CC, b1, p1, pn + 1, H, ysc);
  k_pool<<<dim3(4, BB), 256, 0, stream>>>(ysc, m, ncur + 1*BB, ncur + 2*BB, gate);
  k_deg<<<dim3(4, BB), 256, 0, stream>>>(idx, cnt, m, gate, D, dg);

  // ---- stage 3: H -> H (pristine k_lin) ----
  k_aggt<<<BB*NN, 128, 0, stream>>>(idx, cnt, D, dg, m, gate, H, T);
  k_lin<<<dim3(25, BB), 256, 0, stream>>>(T, m, Wt + 2*FF*CC, b2, H);

  // ---- global max pool + FC ----
  k_fmax<<<dim3(8, BB), 128, 0, stream>>>(H, m, part);
  k_fc<<<BB, 128, 0, stream>>>(part, Wfc, bfc, out);
}

// Round 11
// 462.968 us; speedup vs baseline: 3.7456x; 3.7456x over previous
//
#include <hip/hip_runtime.h>
#include <math.h>

#define BB 32
#define NN 1000
#define CC 128
#define FF 128
#define OO 64
#define CAP 128
#define NB 40

// exact replica of JAX's np.float32(1.0 - 0.8) = 0.20000000298023224f
#define RMC ((float)(1.0 - 0.8))

// ---- CSR build + stage-1 D/dg + fused pre-work (blocks with i==NN) ----
// masked rows (all-zero in A, pre-masked) skipped.
__global__ void k_csr(const float* __restrict__ A, const float* __restrict__ mask,
                      const int* __restrict__ Nn,
                      const float* __restrict__ p0, const float* __restrict__ p1,
                      const float* __restrict__ W0, const float* __restrict__ W1,
                      const float* __restrict__ W2,
                      short* __restrict__ idx, int* __restrict__ cnt,
                      float* __restrict__ D, float* __restrict__ dg,
                      float* __restrict__ m, float* __restrict__ gate,
                      int* __restrict__ ncur0, float* __restrict__ pn,
                      float* __restrict__ Wt){
  int i = blockIdx.x, b = blockIdx.y, lane = threadIdx.x;   // block = 64 (one wave)
  if (i == NN){                            // ---- 32 pre-work blocks ----
    for (int j = lane; j < NN; j += 64){
      float v = mask[b*NN + j]; m[b*NN + j] = v; gate[b*NN + j] = v;
    }
    if (lane == 0) ncur0[b] = Nn[b];
    if (b == 0 && lane == 1){ float s=0.f; for(int c=0;c<FF;c++) s += p0[c]*p0[c]; pn[0] = sqrtf(s); }
    if (b == 1 && lane == 1){ float s=0.f; for(int c=0;c<FF;c++) s += p1[c]*p1[c]; pn[1] = sqrtf(s); }
    // Wt[s][c][f] = W[s][f][c]; 3*FF*CC = 49152 elems, 1536 per block
    for (int e = b*1536 + lane; e < (b+1)*1536; e += 64){
      int s = e / (FF*CC), rem = e % (FF*CC);
      int c = rem >> 7, f = rem & 127;
      const float* W = (s == 0) ? W0 : (s == 1) ? W1 : W2;
      Wt[(size_t)s*FF*CC + rem] = W[f*CC + c];
    }
    return;
  }
  if (mask[b*NN + i] == 0.f){              // A row is all-zero (A pre-masked)
    if (lane == 0){
      cnt[b*NN + i] = 0;
      D[b*NN + i]  = 1.0f / sqrtf(1.0f + 1e-5f);
      dg[b*NN + i] = 0.f;
    }
    return;
  }
  const float4* row = (const float4*)(A + ((size_t)b*NN + i)*NN);
  short* out = idx + ((size_t)b*NN + i)*CAP;
  int count = 0;
  for (int base = 0; base < 250; base += 64){               // 1000 = 250 float4
    int q = base + lane;
    float4 v;
    if (q < 250) v = row[q]; else { v.x=v.y=v.z=v.w=0.f; }
    int lc = (v.x!=0.f) + (v.y!=0.f) + (v.z!=0.f) + (v.w!=0.f);
    int pre = lc;
    #pragma unroll
    for (int off = 1; off < 64; off <<= 1){
      int t = __shfl_up(pre, off);
      if (lane >= off) pre += t;
    }
    int tot = __shfl(pre, 63);
    pre -= lc;                                              // exclusive prefix
    int slot = count + pre;
    int j = q*4;
    if (v.x!=0.f && slot < CAP) out[slot++] = (short)j;
    if (v.y!=0.f && slot < CAP) out[slot++] = (short)(j+1);
    if (v.z!=0.f && slot < CAP) out[slot++] = (short)(j+2);
    if (v.w!=0.f && slot < CAP) out[slot++] = (short)(j+3);
    count += tot;
  }
  if (lane == 0){
    int cn = (count < CAP) ? count : CAP;
    cnt[b*NN + i] = cn;
    // stage-1 degree: A pre-masked => every CSR neighbor has mask=1
    float Dv = 1.0f / sqrtf((float)cn + 1.0f + 1e-5f);
    D[b*NN + i]  = Dv;
    dg[b*NN + i] = Dv;                   // mask_i == 1 here
  }
}

// ---- Y_i = sum_nbr dg_j*h_j ; T_i = D_i*Y + D_i^2*(gate_i*h_i) ----
// float4 gather (16 B/lane), 4 groups of 32 lanes; staging-time compaction drops
// dn==0 edges (order-preserving); gather loop branch-free (R6 lesson).
__global__ void k_aggt(const short* __restrict__ idx, const int* __restrict__ cnt,
                       const float* __restrict__ D, const float* __restrict__ dg,
                       const float* __restrict__ m, const float* __restrict__ gate,
                       const float* __restrict__ h, float* __restrict__ T){
  __shared__ int   nb[CAP];                // row offsets j*CC (compacted)
  __shared__ float dn[CAP];
  __shared__ float red[4][CC];             // cross-group partials (2 KB)
  __shared__ int   wtot[2];
  int blk = blockIdx.x;                    // XCD swizzle: same b lands on same XCD
  int b = (blk & 7) + 8*((blk >> 3) & 3);
  int i = blk >> 5;
  int tid = threadIdx.x;                   // block = 128
  size_t orow = ((size_t)b*NN + i)*CC;
  if (m[b*NN + i] == 0.f){                 // masked target: T row must be zero
    T[orow + tid] = 0.f;
    return;
  }
  int n = cnt[b*NN + i];
  const short* r = idx + ((size_t)b*NN + i)*CAP;
  // --- compaction: keep edges with dn != 0, preserve order ---
  int j = 0; float d = 0.f; bool keep = false;
  if (tid < n){ j = (int)r[tid]; d = dg[b*NN + j]; keep = (d != 0.f); }
  unsigned long long ball = __ballot(keep);
  int lane64 = tid & 63, wv = tid >> 6;
  int pre = __popcll(ball & ((1ull << lane64) - 1ull));
  if (lane64 == 0) wtot[wv] = __popcll(ball);
  __syncthreads();
  int base = (wv == 1) ? wtot[0] : 0;
  if (keep){ nb[base + pre] = j*CC; dn[base + pre] = d; }
  int nlive = wtot[0] + wtot[1];
  int np = (nlive + 15) & ~15;             // pad to 16 (CAP=128 safe)
  for (int q = nlive + tid; q < np; q += 128){ nb[q] = 0; dn[q] = 0.f; }
  __syncthreads();
  // --- branch-free float4 gather: group g handles edges k+g, k+g+4, k+g+8, k+g+12 ---
  int g = tid >> 5, lane = tid & 31;
  const float* hb = h + (size_t)b*NN*CC;
  float4 a0 = {0.f,0.f,0.f,0.f}, a1 = a0, a2 = a0, a3 = a0;
  for (int k = 0; k < np; k += 16){
    int e = k + g;
    float4 v0 = *(const float4*)(hb + nb[e   ] + (lane<<2));
    float4 v1 = *(const float4*)(hb + nb[e+ 4] + (lane<<2));
    float4 v2 = *(const float4*)(hb + nb[e+ 8] + (lane<<2));
    float4 v3 = *(const float4*)(hb + nb[e+12] + (lane<<2));
    float d0 = dn[e], d1 = dn[e+4], d2 = dn[e+8], d3 = dn[e+12];
    a0.x += d0*v0.x; a0.y += d0*v0.y; a0.z += d0*v0.z; a0.w += d0*v0.w;
    a1.x += d1*v1.x; a1.y += d1*v1.y; a1.z += d1*v1.z; a1.w += d1*v1.w;
    a2.x += d2*v2.x; a2.y += d2*v2.y; a2.z += d2*v2.z; a2.w += d2*v2.w;
    a3.x += d3*v3.x; a3.y += d3*v3.y; a3.z += d3*v3.z; a3.w += d3*v3.w;
  }
  float4 Yv;
  Yv.x = (a0.x + a1.x) + (a2.x + a3.x);
  Yv.y = (a0.y + a1.y) + (a2.y + a3.y);
  Yv.z = (a0.z + a1.z) + (a2.z + a3.z);
  Yv.w = (a0.w + a1.w) + (a2.w + a3.w);
  *(float4*)&red[g][lane<<2] = Yv;
  __syncthreads();
  int c = tid;
  float Y = (red[0][c] + red[1][c]) + (red[2][c] + red[3][c]);
  float Di = D[b*NN + i];
  float gi = gate[b*NN + i];
  T[orow + c] = Di*Y + Di*Di*(gi*hb[(size_t)i*CC + c]);
}

// ---- H = relu(T @ W^T + b)*m ----
// FROZEN R3 GEMM body. Empirical law (R4/R5/R10, three confirmations): ANY addition
// to this kernel (launch_bounds, score epilogue, extra LDS) flips the allocator's
// occupancy heuristic to VGPR=64/128 and spills the accumulators: ~1.6 GB phantom
// HBM traffic, 590-720 µs vs <75 µs. Do not decorate. Score stays a separate kernel.
__global__ void k_lin(const float* __restrict__ T, const float* __restrict__ m,
                      const float* __restrict__ Wt,   // [cc][f] transposed
                      const float* __restrict__ bias, float* __restrict__ Hout){
  __shared__ float t[NB][CC];              // 20.5 KB
  int b = blockIdx.y, tid = threadIdx.x;   // block = 256
  int i0 = blockIdx.x * NB;
  const float4* Tg = (const float4*)(T + ((size_t)b*NN + i0)*CC);
  float4* tl = (float4*)&t[0][0];
  #pragma unroll
  for (int e = 0; e < 5; e++) tl[tid + e*256] = Tg[tid + e*256];  // 1280 float4
  __syncthreads();
  int fg = tid & 31;                       // 4 consecutive f per thread
  int nr = tid >> 5;                       // 0..7 node-row
  float acc[5][4];
  float4 bi = ((const float4*)bias)[fg];
  #pragma unroll
  for (int n5 = 0; n5 < 5; n5++){
    acc[n5][0]=bi.x; acc[n5][1]=bi.y; acc[n5][2]=bi.z; acc[n5][3]=bi.w;
  }
  for (int c4 = 0; c4 < 32; c4++){
    float4 tv[5];
    #pragma unroll
    for (int n5 = 0; n5 < 5; n5++)
      tv[n5] = *((const float4*)&t[nr + n5*8][c4*4]);
    #pragma unroll
    for (int k = 0; k < 4; k++){
      float4 wv = ((const float4*)Wt)[(size_t)(c4*4 + k)*32 + fg];
      #pragma unroll
      for (int n5 = 0; n5 < 5; n5++){
        float tvv = (k==0) ? tv[n5].x : (k==1) ? tv[n5].y : (k==2) ? tv[n5].z : tv[n5].w;
        acc[n5][0] += tvv*wv.x; acc[n5][1] += tvv*wv.y;
        acc[n5][2] += tvv*wv.z; acc[n5][3] += tvv*wv.w;
      }
    }
  }
  #pragma unroll
  for (int n5 = 0; n5 < 5; n5++){
    int i = i0 + nr + n5*8;
    float mi = m[b*NN + i];
    float4 o4;
    o4.x = fmaxf(acc[n5][0], 0.f)*mi;
    o4.y = fmaxf(acc[n5][1], 0.f)*mi;
    o4.z = fmaxf(acc[n5][2], 0.f)*mi;
    o4.w = fmaxf(acc[n5][3], 0.f)*mi;
    ((float4*)&Hout[((size_t)b*NN + i)*CC])[fg] = o4;
  }
}

// ---------------- pool scores y_i = (H_i . p) / |p| ----------------
__global__ void k_score(const float* __restrict__ H, const float* __restrict__ p,
                        const float* __restrict__ pn, float* __restrict__ y){
  int i = blockIdx.x, b = blockIdx.y, lane = threadIdx.x;  // block = 64
  const float* hrow = H + ((size_t)b*NN + i)*CC;
  float s = hrow[lane]*p[lane] + hrow[lane+64]*p[lane+64];
  for (int off = 32; off > 0; off >>= 1) s += __shfl_down(s, off);
  if (lane == 0) y[b*NN + i] = s / pn[0];
}

// ---------------- top-k pool: 1 node/thread, float4 LDS scan, ping-pong ncur ----------------
__global__ void k_pool(const float* __restrict__ y, float* __restrict__ m,
                       const int* __restrict__ ncur_in, int* __restrict__ ncur_out,
                       float* __restrict__ gate){
  __shared__ float yk[NN];
  int b = blockIdx.y, tid = threadIdx.x;   // grid (4, BB), block = 256
  int i = blockIdx.x*256 + tid;
  for (int j = tid; j < NN; j += 256)
    yk[j] = (m[b*NN + j] > 0.f) ? y[b*NN + j] : INFINITY;
  __syncthreads();
  int n = ncur_in[b];
  int nr = (int)((float)n * RMC);          // exact JAX semantics (f32 mult, trunc)
  float myv = (i < NN) ? yk[i] : INFINITY;
  int cnt = 0;
  const float4* yk4 = (const float4*)yk;   // broadcast reads: conflict-free
  #pragma unroll 5
  for (int q = 0; q < 250; q++){
    float4 v = yk4[q];
    int j0 = q*4;
    cnt += (int)((v.x < myv) || (v.x == myv && j0     < i));
    cnt += (int)((v.y < myv) || (v.y == myv && j0 + 1 < i));
    cnt += (int)((v.z < myv) || (v.z == myv && j0 + 2 < i));
    cnt += (int)((v.w < myv) || (v.w == myv && j0 + 3 < i));
  }
  if (i < NN){
    bool keep = (cnt >= nr) && (m[b*NN + i] > 0.f);
    m[b*NN + i]    = keep ? 1.0f : 0.0f;
    gate[b*NN + i] = keep ? tanhf(y[b*NN + i]) : 0.0f;
  }
  if (blockIdx.x == 0 && tid == 0) ncur_out[b] = n - nr;
}

// ---------------- degree from new mask -> D, dg = D*gate ----------------
__global__ void k_deg(const short* __restrict__ idx, const int* __restrict__ cnt,
                      const float* __restrict__ m, const float* __restrict__ gate,
                      float* __restrict__ D, float* __restrict__ dg){
  __shared__ float ml[NN];
  int b = blockIdx.y, tid = threadIdx.x;   // grid (4, BB), block = 256
  for (int i = tid; i < NN; i += 256) ml[i] = m[b*NN + i];
  __syncthreads();
  int j = blockIdx.x*250 + tid;
  if (tid < 250){
    const short* r = idx + ((size_t)b*NN + j)*CAP;
    int n = cnt[b*NN + j];
    float s0=0.f, s1=0.f, s2=0.f, s3=0.f;
    int k = 0;
    for (; k+4 <= n; k += 4){
      s0 += ml[r[k]]; s1 += ml[r[k+1]]; s2 += ml[r[k+2]]; s3 += ml[r[k+3]];
    }
    for (; k < n; k++) s0 += ml[r[k]];
    float Dv = 1.0f / sqrtf(((s0+s1)+(s2+s3)) + 1.0f + 1e-5f);
    D[b*NN + j]  = Dv;
    dg[b*NN + j] = Dv * gate[b*NN + j];
  }
}

// ---------------- partial global max pool (masked rows skipped; relu => max>=0) ----------------
__global__ void k_fmax(const float* __restrict__ H, const float* __restrict__ m,
                       float* __restrict__ part){
  int sx = blockIdx.x, b = blockIdx.y, c = threadIdx.x;   // grid (8, BB), block = 128
  float mx = 0.f;
  int i0 = sx*125;
  for (int i = i0; i < i0+125; i++){
    if (m[b*NN + i] != 0.f)
      mx = fmaxf(mx, H[((size_t)b*NN + i)*CC + c]);
  }
  part[((size_t)b*8 + sx)*CC + c] = mx;
}

// ---------------- combine partial maxima + FC ----------------
__global__ void k_fc(const float* __restrict__ part, const float* __restrict__ Wfc,
                     const float* __restrict__ bfc, float* __restrict__ out){
  __shared__ float g[FF];
  int b = blockIdx.x, tid = threadIdx.x;   // block = 128
  float mx = 0.f;
  #pragma unroll
  for (int s = 0; s < 8; s++) mx = fmaxf(mx, part[((size_t)b*8 + s)*CC + tid]);
  g[tid] = mx;
  __syncthreads();
  if (tid < OO){
    float acc = bfc[tid];
    for (int c = 0; c < FF; c++) acc += g[c]*Wfc[tid*FF + c];
    out[b*OO + tid] = acc;
  }
}

extern "C" void kernel_launch(void* const* d_in, const int* in_sizes, int n_in,
                              void* d_out, int out_size, void* d_ws, size_t ws_size,
                              hipStream_t stream) {
  const float* x    = (const float*)d_in[0];
  const float* A    = (const float*)d_in[1];
  const float* mask = (const float*)d_in[2];
  const int*   Nn   = (const int*)  d_in[3];
  const float* W0   = (const float*)d_in[4];
  const float* b0   = (const float*)d_in[5];
  const float* W1   = (const float*)d_in[6];
  const float* b1   = (const float*)d_in[7];
  const float* W2   = (const float*)d_in[8];
  const float* b2   = (const float*)d_in[9];
  const float* p0   = (const float*)d_in[10];
  const float* p1   = (const float*)d_in[11];
  const float* Wfc  = (const float*)d_in[12];
  const float* bfc  = (const float*)d_in[13];
  float* out = (float*)d_out;

  // workspace carve (~42 MB)
  char* w = (char*)d_ws;
  float* H   = (float*)w; w += (size_t)BB*NN*CC*4;      // 16.38 MB
  float* T   = (float*)w; w += (size_t)BB*NN*CC*4;      // 16.38 MB
  short* idx = (short*)w; w += (size_t)BB*NN*CAP*2;     // 8.19 MB
  float* Wt  = (float*)w; w += (size_t)3*FF*CC*4;       // 192 KB
  float* part= (float*)w; w += (size_t)8*BB*CC*4;       // 131 KB
  int*   cnt = (int*)w;   w += (size_t)BB*NN*4;
  float* D   = (float*)w; w += (size_t)BB*NN*4;
  float* m   = (float*)w; w += (size_t)BB*NN*4;
  float* ysc = (float*)w; w += (size_t)BB*NN*4;
  float* gate= (float*)w; w += (size_t)BB*NN*4;
  float* dg  = (float*)w; w += (size_t)BB*NN*4;
  int*   ncur= (int*)w;   w += 3*BB*sizeof(int);        // ping-pong slots
  float* pn  = (float*)w; w += 64;

  // CSR + all pre-work in one dispatch (grid has 32 extra i==NN blocks)
  k_csr<<<dim3(NN + 1, BB), 64, 0, stream>>>(A, mask, Nn, p0, p1, W0, W1, W2,
                                             idx, cnt, D, dg, m, gate, ncur, pn, Wt);

  // ---- stage 1: x -> H ----
  k_aggt<<<BB*NN, 128, 0, stream>>>(idx, cnt, D, dg, m, gate, x, T);
  k_lin<<<dim3(25, BB), 256, 0, stream>>>(T, m, Wt + 0*FF*CC, b0, H);
  k_score<<<dim3(NN, BB), 64, 0, stream>>>(H, p0, pn + 0, ysc);
  k_pool<<<dim3(4, BB), 256, 0, stream>>>(ysc, m, ncur + 0*BB, ncur + 1*BB, gate);
  k_deg<<<dim3(4, BB), 256, 0, stream>>>(idx, cnt, m, gate, D, dg);

  // ---- stage 2: H -> H ----
  k_aggt<<<BB*NN, 128, 0, stream>>>(idx, cnt, D, dg, m, gate, H, T);
  k_lin<<<dim3(25, BB), 256, 0, stream>>>(T, m, Wt + 1*FF*CC, b1, H);
  k_score<<<dim3(NN, BB), 64, 0, stream>>>(H, p1, pn + 1, ysc);
  k_pool<<<dim3(4, BB), 256, 0, stream>>>(ysc, m, ncur + 1*BB, ncur + 2*BB, gate);
  k_deg<<<dim3(4, BB), 256, 0, stream>>>(idx, cnt, m, gate, D, dg);

  // ---- stage 3: H -> H ----
  k_aggt<<<BB*NN, 128, 0, stream>>>(idx, cnt, D, dg, m, gate, H, T);
  k_lin<<<dim3(25, BB), 256, 0, stream>>>(T, m, Wt + 2*FF*CC, b2, H);

  // ---- global max pool + FC ----
  k_fmax<<<dim3(8, BB), 128, 0, stream>>>(H, m, part);
  k_fc<<<BB, 128, 0, stream>>>(part, Wfc, bfc, out);
}